// Round 3
// baseline (6201.595 us; speedup 1.0000x reference)
//
#include <hip/hip_runtime.h>
#include <stdint.h>

// AutoregressiveRAM: 4095 serial steps of an 8192-neuron weightless NN.
// Persistent 32-block kernel (256 thr = 1 neuron each); per-step state
// (8192 bits = 256 words) exchanged via tagged (data32 lo, tag32 hi) 64-bit
// agent-scope atomics in d_ws. Transition RAM prepacked to bits (32MB->1MB),
// and each block's 32KB slice is staged in LDS so the data-dependent lookup
// never leaves the CU. LDS state is double-buffered -> ONE barrier per step.
//
// Race-freedom: state s lives in LDS buf[s&1] and mailbox slot[s&1] (tag s+1).
// Iter i: poll remote words of state i-1 into buf[(i-1)&1], barrier, gather,
// publish state i to slot[i&1] + own words direct to buf[i&1]. A buffer/slot
// is only overwritten at iter i+2, and tag i+2 visibility requires every
// block to have passed iter i+1's poll (hence its barrier, hence finished all
// iter-i reads of that buffer/slot). Exact-tag matching makes stale mailbox
// contents harmless; a memset node additionally zeroes it each replay.

#define BITS   8192
#define NBT    10
#define NBLK   32
#define TPB    256
#define NPB    (BITS / NBLK)   // 256 neurons per block (1 per thread)
#define SWORDS 256             // 8192 state bits / 32
#define WPB    (NPB / 32)      // 8 state words owned per block
#define TWORDS (NPB * 32)      // 8192 lookup-table words per block (32 KB)
#define FUSE   (1 << 12)       // bounded spin; protocol slack is ~10 iters

__global__ void pack_kernel(const float* __restrict__ tm, uint32_t* __restrict__ packed) {
    // 8192*1024 floats -> 262144 packed u32 words. One float per thread.
    int tid = blockIdx.x * blockDim.x + threadIdx.x;
    float v = tm[tid];
    unsigned long long m = __ballot(v > 0.5f);
    int lane = tid & 63;
    if ((lane & 31) == 0) {
        packed[tid >> 5] = (lane == 0) ? (uint32_t)m : (uint32_t)(m >> 32);
    }
}

__global__ __launch_bounds__(TPB) void ram_step_kernel(
    const int* __restrict__ conn,        // [8192][10]
    const float* __restrict__ init_mem,  // [8192][16]
    const uint32_t* __restrict__ packedT,// [8192][32]
    unsigned long long* __restrict__ pairs, // [2][SWORDS] (data lo32, tag hi32)
    float* __restrict__ out,             // [length][8192]
    int length)
{
    const int b = blockIdx.x;
    const int t = threadIdx.x;
    const int lane = t & 63;
    const int n = b * NPB + t;           // this thread's neuron

    __shared__ uint32_t st[2][SWORDS + 1];   // double-buffered state + pos word
    __shared__ uint32_t tbl[TWORDS];         // this block's packed RAM slice

    // Stage this block's 32KB lookup slice into LDS (8 x dwordx4 per thread).
    {
        const uint32_t* tp = packedT + (size_t)b * TWORDS;
#pragma unroll
        for (int k = 0; k < 8; ++k) {
            int w = k * 1024 + t * 4;
            uint4 v = *(const uint4*)(tp + w);
            *(uint4*)&tbl[w] = v;
        }
    }

    // Connections are static: registers for the whole run.
    int c[NBT];
#pragma unroll
    for (int j = 0; j < NBT; ++j) c[j] = conn[n * NBT + j];

    const int gw = b * WPB + (t >> 6) * 2;   // this wave's global state-word base

    // ---- step 0: pos bits of 0 are all zero -> addr 0 -> initial_memory[:,0]
    float v0 = init_mem[n << 4];
    int bit = (v0 > 0.5f) ? 1 : 0;
    unsigned long long m = __ballot(bit);
    if (lane == 0) {
        const unsigned long long tag = 1ull << 32;  // tag(state s) = s+1
        __hip_atomic_store(&pairs[gw],     tag | (uint32_t)m,
                           __ATOMIC_RELAXED, __HIP_MEMORY_SCOPE_AGENT);
        __hip_atomic_store(&pairs[gw + 1], tag | (uint32_t)(m >> 32),
                           __ATOMIC_RELAXED, __HIP_MEMORY_SCOPE_AGENT);
        st[0][gw]     = (uint32_t)m;         // own slice direct to LDS buf 0
        st[0][gw + 1] = (uint32_t)(m >> 32);
    }
    out[n] = v0;

    for (int i = 1; i < length; ++i) {
        uint32_t* sb = st[(i - 1) & 1];          // buffer holding state i-1
        const uint32_t want = (uint32_t)i;       // tag of state i-1

        if (t == 0) {
            // pos bits of step i: x[8192+j] = (i >> (3-j)) & 1, j=0..3
            sb[SWORDS] = ((i >> 3) & 1) | (((i >> 2) & 1) << 1) |
                         (((i >> 1) & 1) << 2) | ((i & 1) << 3);
        }
        if ((t >> 3) != b) {                     // poll all remote state words
            unsigned long long* p = &pairs[((i - 1) & 1) * SWORDS + t];
            unsigned long long pv;
            int fuse = 0;
            do {
                pv = __hip_atomic_load(p, __ATOMIC_RELAXED, __HIP_MEMORY_SCOPE_AGENT);
            } while ((uint32_t)(pv >> 32) != want && ++fuse < FUSE);
            sb[t] = (uint32_t)pv;
        }
        __syncthreads();                          // fills visible; gather below

        // gather 10 bits -> 10-bit address (conn[0] is MSB)
        uint32_t addr = 0;
#pragma unroll
        for (int j = 0; j < NBT; ++j) {
            int cc = c[j];
            addr = (addr << 1) | ((sb[cc >> 5] >> (cc & 31)) & 1u);
        }
        uint32_t pw = tbl[(t << 5) + (addr >> 5)];   // LDS lookup (~120cy)
        bit = (pw >> (addr & 31)) & 1;

        // publish state i FIRST (critical path), then the output store
        m = __ballot(bit);
        if (lane == 0) {
            const unsigned long long tag = ((unsigned long long)(i + 1)) << 32;
            const int base = (i & 1) * SWORDS + gw;
            __hip_atomic_store(&pairs[base],     tag | (uint32_t)m,
                               __ATOMIC_RELAXED, __HIP_MEMORY_SCOPE_AGENT);
            __hip_atomic_store(&pairs[base + 1], tag | (uint32_t)(m >> 32),
                               __ATOMIC_RELAXED, __HIP_MEMORY_SCOPE_AGENT);
            st[i & 1][gw]     = (uint32_t)m;     // own slice direct to LDS
            st[i & 1][gw + 1] = (uint32_t)(m >> 32);
        }
        out[(size_t)i * BITS + n] = (float)bit;
    }
}

extern "C" void kernel_launch(void* const* d_in, const int* in_sizes, int n_in,
                              void* d_out, int out_size, void* d_ws, size_t ws_size,
                              hipStream_t stream) {
    const float* tm = (const float*)d_in[0];     // transition_memory [8192][1024]
    const float* im = (const float*)d_in[1];     // initial_memory    [8192][16]
    const int*   tc = (const int*)d_in[2];       // transition_connections [8192][10]
    // d_in[3] (initial_connections) is provably unused: pos_bits(0)==0 -> addr 0.
    const int length = out_size / BITS;

    uint32_t* packed = (uint32_t*)d_ws;                                   // 1 MB
    unsigned long long* pairs =
        (unsigned long long*)((char*)d_ws + (1 << 20));                   // 4 KB

    // Clean mailbox every call/replay (graph-capturable memset node).
    hipMemsetAsync(pairs, 0, 2 * SWORDS * sizeof(unsigned long long), stream);

    // Pack transition RAM to bits: 8192*1024 floats, 1 thread each.
    pack_kernel<<<dim3((BITS * 1024) / 256), dim3(256), 0, stream>>>(tm, packed);

    // Persistent recurrence kernel: 32 blocks (always co-resident on 256 CUs).
    ram_step_kernel<<<dim3(NBLK), dim3(TPB), 0, stream>>>(
        tc, im, packed, pairs, (float*)d_out, length);
}